// Round 1
// baseline (88.679 us; speedup 1.0000x reference)
//
#include <hip/hip_runtime.h>
#include <math.h>

#define TRI_EPS 1e-4f

// ---------------- mean(v) over V rows of 3 ----------------
__global__ void vmean_kernel(const float* __restrict__ v, int V,
                             float* __restrict__ ws) {
    __shared__ float sx[256], sy[256], sz[256];
    int t = threadIdx.x;
    float x = 0.f, y = 0.f, z = 0.f;
    for (int i = t; i < V; i += 256) {
        x += v[3 * i + 0];
        y += v[3 * i + 1];
        z += v[3 * i + 2];
    }
    sx[t] = x; sy[t] = y; sz[t] = z;
    __syncthreads();
    for (int off = 128; off > 0; off >>= 1) {
        if (t < off) {
            sx[t] += sx[t + off];
            sy[t] += sy[t + off];
            sz[t] += sz[t + off];
        }
        __syncthreads();
    }
    if (t == 0) {
        ws[0] = sx[0] / (float)V;
        ws[1] = sy[0] / (float)V;
        ws[2] = sz[0] / (float)V;
    }
}

// point-to-segment, matching reference seg():
//   s = clip(dot(ref - p, e)/|e|^2, 0, 1); cl = s*q0 + (1-s)*q1; d = |cl - p|
__device__ __forceinline__ void seg_dist(
    float ex, float ey, float ez,
    float rx, float ry, float rz,
    float q0x, float q0y, float q0z,
    float q1x, float q1y, float q1z,
    float px, float py, float pz,
    float& d, float& clx, float& cly, float& clz) {
    float m2 = ex * ex + ey * ey + ez * ez;
    float s = ((rx - px) * ex + (ry - py) * ey + (rz - pz) * ez) / m2;
    s = fminf(fmaxf(s, 0.f), 1.f);
    float om = 1.f - s;
    clx = s * q0x + om * q1x;
    cly = s * q0y + om * q1y;
    clz = s * q0z + om * q1z;
    float ddx = clx - px, ddy = cly - py, ddz = clz - pz;
    d = sqrtf(ddx * ddx + ddy * ddy + ddz * ddz);
}

__global__ __launch_bounds__(256) void sdf_kernel(
    const float* __restrict__ p, const float* __restrict__ v,
    const int* __restrict__ f, const float* __restrict__ vmean,
    float* __restrict__ out, int N, int F) {
    const int i = blockIdx.x;   // point index
    const int t = threadIdx.x;

    const float px = p[3 * i + 0];
    const float py = p[3 * i + 1];
    const float pz = p[3 * i + 2];
    const float dirx = vmean[0] - px;
    const float diry = vmean[1] - py;
    const float dirz = vmean[2] - pz;

    float bestd = INFINITY;
    int bestj = 0x7fffffff;
    float bcx = 0.f, bcy = 0.f, bcz = 0.f;
    int hits = 0;

    for (int j = t; j < F; j += 256) {
        const int i0 = f[3 * j + 0];
        const int i1 = f[3 * j + 1];
        const int i2 = f[3 * j + 2];
        const float ax = v[3 * i0 + 0], ay = v[3 * i0 + 1], az = v[3 * i0 + 2];
        const float bx = v[3 * i1 + 0], by = v[3 * i1 + 1], bz = v[3 * i1 + 2];
        const float cx = v[3 * i2 + 0], cy = v[3 * i2 + 1], cz = v[3 * i2 + 2];

        // --- three edge distances, reference order: (e1,a,b,a) (e2,c,b,c) (e3,c,a,c)
        float d1, x1, y1, z1;
        seg_dist(ax - bx, ay - by, az - bz,  ax, ay, az,
                 bx, by, bz,  ax, ay, az,  px, py, pz, d1, x1, y1, z1);
        float d2, x2, y2, z2;
        seg_dist(cx - bx, cy - by, cz - bz,  cx, cy, cz,
                 bx, by, bz,  cx, cy, cz,  px, py, pz, d2, x2, y2, z2);
        float d3, x3, y3, z3;
        seg_dist(cx - ax, cy - ay, cz - az,  cx, cy, cz,
                 ax, ay, az,  cx, cy, cz,  px, py, pz, d3, x3, y3, z3);

        // argmin over the 3 edges, first-occurrence semantics
        float fd = d1, fx = x1, fy = y1, fz = z1;
        if (d2 < fd) { fd = d2; fx = x2; fy = y2; fz = z2; }
        if (d3 < fd) { fd = d3; fx = x3; fy = y3; fz = z3; }

        // thread-local argmin across faces (ascending j => first-occurrence)
        if (fd < bestd) {
            bestd = fd; bestj = j;
            bcx = fx; bcy = fy; bcz = fz;
        }

        // --- Moller-Trumbore ray hit (dir = vmean - p), reference formulas
        const float m1x = bx - ax, m1y = by - ay, m1z = bz - az;  // me1 = b - a
        const float m2x = cx - ax, m2y = cy - ay, m2z = cz - az;  // me2 = c - a
        // pvec = cross(dir, me2)
        const float pvx = diry * m2z - dirz * m2y;
        const float pvy = dirz * m2x - dirx * m2z;
        const float pvz = dirx * m2y - diry * m2x;
        const float det = m1x * pvx + m1y * pvy + m1z * pvz;
        if (fabsf(det) > TRI_EPS) {
            const float tvx = px - ax, tvy = py - ay, tvz = pz - az;
            const float u = (tvx * pvx + tvy * pvy + tvz * pvz) / det;
            // qvec = cross(tvec, me1)
            const float qvx = tvy * m1z - tvz * m1y;
            const float qvy = tvz * m1x - tvx * m1z;
            const float qvz = tvx * m1y - tvy * m1x;
            const float dd = (dirx * qvx + diry * qvy + dirz * qvz) / det;
            const float tt = (m2x * qvx + m2y * qvy + m2z * qvz) / det;
            if (u >= 0.f && u <= 1.f && dd >= 0.f && (u + dd) <= 1.f &&
                tt > TRI_EPS) {
                hits++;
            }
        }
    }

    // ---------------- block reduction ----------------
    __shared__ float sd[256];
    __shared__ int   sj[256];
    __shared__ float scx[256], scy[256], scz[256];
    __shared__ int   sh[256];
    sd[t] = bestd; sj[t] = bestj;
    scx[t] = bcx; scy[t] = bcy; scz[t] = bcz;
    sh[t] = hits;
    __syncthreads();
    for (int off = 128; off > 0; off >>= 1) {
        if (t < off) {
            const float dov = sd[t + off];
            const int   jov = sj[t + off];
            if (dov < sd[t] || (dov == sd[t] && jov < sj[t])) {
                sd[t] = dov; sj[t] = jov;
                scx[t] = scx[t + off];
                scy[t] = scy[t + off];
                scz[t] = scz[t + off];
            }
            sh[t] += sh[t + off];
        }
        __syncthreads();
    }
    if (t == 0) {
        const float sign = (sh[0] & 1) ? -1.f : 1.f;
        out[i] = sd[0] * sign;
        out[N + 3 * i + 0] = scx[0];
        out[N + 3 * i + 1] = scy[0];
        out[N + 3 * i + 2] = scz[0];
    }
}

extern "C" void kernel_launch(void* const* d_in, const int* in_sizes, int n_in,
                              void* d_out, int out_size, void* d_ws,
                              size_t ws_size, hipStream_t stream) {
    const float* p = (const float*)d_in[0];
    const float* v = (const float*)d_in[1];
    const int* f = (const int*)d_in[2];
    float* out = (float*)d_out;
    float* ws = (float*)d_ws;

    const int N = in_sizes[0] / 3;
    const int V = in_sizes[1] / 3;
    const int F = in_sizes[2] / 3;

    vmean_kernel<<<1, 256, 0, stream>>>(v, V, ws);
    sdf_kernel<<<N, 256, 0, stream>>>(p, v, f, ws, out, N, F);
}

// Round 2
// 46.261 us; speedup vs baseline: 1.9169x; 1.9169x over previous
//
#include <hip/hip_runtime.h>
#include <math.h>

#define TRI_EPS 1e-4f

// ---------------- mean(v) over V rows of 3 ----------------
__global__ void vmean_kernel(const float* __restrict__ v, int V,
                             float* __restrict__ ws) {
    __shared__ float sx[256], sy[256], sz[256];
    int t = threadIdx.x;
    float x = 0.f, y = 0.f, z = 0.f;
    for (int i = t; i < V; i += 256) {
        x += v[3 * i + 0];
        y += v[3 * i + 1];
        z += v[3 * i + 2];
    }
    sx[t] = x; sy[t] = y; sz[t] = z;
    __syncthreads();
    for (int off = 128; off > 0; off >>= 1) {
        if (t < off) {
            sx[t] += sx[t + off];
            sy[t] += sy[t + off];
            sz[t] += sz[t + off];
        }
        __syncthreads();
    }
    if (t == 0) {
        ws[0] = sx[0] / (float)V;
        ws[1] = sy[0] / (float)V;
        ws[2] = sz[0] / (float)V;
    }
}

// ---------------- per-face gather + precompute ----------------
// record j: [a.xyz, 1/|a-b|^2] [b.xyz, 1/|c-b|^2] [c.xyz, 1/|c-a|^2]
__global__ __launch_bounds__(256) void prep_kernel(
    const float* __restrict__ v, const int* __restrict__ f,
    float4* __restrict__ fd, int F) {
    int j = blockIdx.x * 256 + threadIdx.x;
    if (j >= F) return;
    const int i0 = f[3 * j + 0];
    const int i1 = f[3 * j + 1];
    const int i2 = f[3 * j + 2];
    const float ax = v[3 * i0 + 0], ay = v[3 * i0 + 1], az = v[3 * i0 + 2];
    const float bx = v[3 * i1 + 0], by = v[3 * i1 + 1], bz = v[3 * i1 + 2];
    const float cx = v[3 * i2 + 0], cy = v[3 * i2 + 1], cz = v[3 * i2 + 2];
    const float e1x = ax - bx, e1y = ay - by, e1z = az - bz;
    const float e2x = cx - bx, e2y = cy - by, e2z = cz - bz;
    const float e3x = cx - ax, e3y = cy - ay, e3z = cz - az;
    const float m1 = e1x * e1x + e1y * e1y + e1z * e1z;
    const float m2 = e2x * e2x + e2y * e2y + e2z * e2z;
    const float m3 = e3x * e3x + e3y * e3y + e3z * e3z;
    fd[3 * j + 0] = make_float4(ax, ay, az, 1.f / m1);
    fd[3 * j + 1] = make_float4(bx, by, bz, 1.f / m2);
    fd[3 * j + 2] = make_float4(cx, cy, cz, 1.f / m3);
}

// one (face, point) interaction; updates running state
__device__ __forceinline__ void pair_update(
    float ax, float ay, float az, float bx, float by, float bz,
    float cx, float cy, float cz, float inv1, float inv2, float inv3,
    float e1x, float e1y, float e1z, float e2x, float e2y, float e2z,
    float e3x, float e3y, float e3z,
    float px, float py, float pz, float dx, float dy, float dz, int j,
    float& bd2, int& bj, float& bcx, float& bcy, float& bcz, int& hits) {
    const float apx = ax - px, apy = ay - py, apz = az - pz;
    const float cpx = cx - px, cpy = cy - py, cpz = cz - pz;

    // seg(e1, a, b, a): cl = s*b + (1-s)*a
    float s1 = (apx * e1x + apy * e1y + apz * e1z) * inv1;
    s1 = fminf(fmaxf(s1, 0.f), 1.f);
    const float o1 = 1.f - s1;
    const float x1 = s1 * bx + o1 * ax;
    const float y1 = s1 * by + o1 * ay;
    const float z1 = s1 * bz + o1 * az;
    float ux = x1 - px, uy = y1 - py, uz = z1 - pz;
    const float d1 = ux * ux + uy * uy + uz * uz;

    // seg(e2, c, b, c): cl = s*b + (1-s)*c
    float s2 = (cpx * e2x + cpy * e2y + cpz * e2z) * inv2;
    s2 = fminf(fmaxf(s2, 0.f), 1.f);
    const float o2 = 1.f - s2;
    const float x2 = s2 * bx + o2 * cx;
    const float y2 = s2 * by + o2 * cy;
    const float z2 = s2 * bz + o2 * cz;
    ux = x2 - px; uy = y2 - py; uz = z2 - pz;
    const float d2 = ux * ux + uy * uy + uz * uz;

    // seg(e3, c, a, c): cl = s*a + (1-s)*c
    float s3 = (cpx * e3x + cpy * e3y + cpz * e3z) * inv3;
    s3 = fminf(fmaxf(s3, 0.f), 1.f);
    const float o3 = 1.f - s3;
    const float x3 = s3 * ax + o3 * cx;
    const float y3 = s3 * ay + o3 * cy;
    const float z3 = s3 * az + o3 * cz;
    ux = x3 - px; uy = y3 - py; uz = z3 - pz;
    const float d3 = ux * ux + uy * uy + uz * uz;

    // first-occurrence argmin over edges (squared dists; exact ties preserved)
    float fd2 = d1, fx = x1, fy = y1, fz = z1;
    if (d2 < fd2) { fd2 = d2; fx = x2; fy = y2; fz = z2; }
    if (d3 < fd2) { fd2 = d3; fx = x3; fy = y3; fz = z3; }
    if (fd2 < bd2) { bd2 = fd2; bj = j; bcx = fx; bcy = fy; bcz = fz; }

    // Moller-Trumbore, division-free.  me1 = -e1, me2 = e3, tvec = -ap.
    const float pvx = dy * e3z - dz * e3y;
    const float pvy = dz * e3x - dx * e3z;
    const float pvz = dx * e3y - dy * e3x;
    const float det = -(e1x * pvx + e1y * pvy + e1z * pvz);
    const float tu = -(apx * pvx + apy * pvy + apz * pvz);
    const float qvx = apy * e1z - apz * e1y;   // == cross(tvec, me1)
    const float qvy = apz * e1x - apx * e1z;
    const float qvz = apx * e1y - apy * e1x;
    const float td = dx * qvx + dy * qvy + dz * qvz;
    const float tn = e3x * qvx + e3y * qvy + e3z * qvz;
    const float adet = fabsf(det);
    const float sd = (det > 0.f) ? 1.f : -1.f;  // exact *1.0 scaling
    const float su = tu * sd;
    const float sq = td * sd;
    const float st = tn * sd;
    if (adet > TRI_EPS && su >= 0.f && su <= adet && sq >= 0.f &&
        (su + sq) <= adet && st > TRI_EPS * adet)
        hits++;
}

__global__ __launch_bounds__(256) void sdf_main(
    const float* __restrict__ p, const float4* __restrict__ fd,
    const float* __restrict__ vm, float* __restrict__ out, int N, int F) {
    const int t = threadIdx.x;
    const int i0 = blockIdx.x * 2;
    const int i1 = i0 + 1;
    const bool has1 = (i1 < N);

    const float vmx = vm[0], vmy = vm[1], vmz = vm[2];
    const float p0x = p[3 * i0 + 0], p0y = p[3 * i0 + 1], p0z = p[3 * i0 + 2];
    const float p1x = has1 ? p[3 * i1 + 0] : 0.f;
    const float p1y = has1 ? p[3 * i1 + 1] : 0.f;
    const float p1z = has1 ? p[3 * i1 + 2] : 0.f;
    const float d0x = vmx - p0x, d0y = vmy - p0y, d0z = vmz - p0z;
    const float d1x = vmx - p1x, d1y = vmy - p1y, d1z = vmz - p1z;

    float Abd2 = INFINITY; int Abj = 0x7fffffff;
    float Acx = 0.f, Acy = 0.f, Acz = 0.f; int Ah = 0;
    float Bbd2 = INFINITY; int Bbj = 0x7fffffff;
    float Bcx = 0.f, Bcy = 0.f, Bcz = 0.f; int Bh = 0;

    for (int j = t; j < F; j += 256) {
        const float4 ra = fd[3 * j + 0];
        const float4 rb = fd[3 * j + 1];
        const float4 rc = fd[3 * j + 2];
        const float ax = ra.x, ay = ra.y, az = ra.z, inv1 = ra.w;
        const float bx = rb.x, by = rb.y, bz = rb.z, inv2 = rb.w;
        const float cx = rc.x, cy = rc.y, cz = rc.z, inv3 = rc.w;
        const float e1x = ax - bx, e1y = ay - by, e1z = az - bz;
        const float e2x = cx - bx, e2y = cy - by, e2z = cz - bz;
        const float e3x = cx - ax, e3y = cy - ay, e3z = cz - az;

        pair_update(ax, ay, az, bx, by, bz, cx, cy, cz, inv1, inv2, inv3,
                    e1x, e1y, e1z, e2x, e2y, e2z, e3x, e3y, e3z,
                    p0x, p0y, p0z, d0x, d0y, d0z, j,
                    Abd2, Abj, Acx, Acy, Acz, Ah);
        pair_update(ax, ay, az, bx, by, bz, cx, cy, cz, inv1, inv2, inv3,
                    e1x, e1y, e1z, e2x, e2y, e2z, e3x, e3y, e3z,
                    p1x, p1y, p1z, d1x, d1y, d1z, j,
                    Bbd2, Bbj, Bcx, Bcy, Bcz, Bh);
    }

    __shared__ float sd2[2][256];
    __shared__ int sjj[2][256];
    __shared__ float scx[2][256], scy[2][256], scz[2][256];
    __shared__ int shh[2][256];
    sd2[0][t] = Abd2; sjj[0][t] = Abj;
    scx[0][t] = Acx; scy[0][t] = Acy; scz[0][t] = Acz; shh[0][t] = Ah;
    sd2[1][t] = Bbd2; sjj[1][t] = Bbj;
    scx[1][t] = Bcx; scy[1][t] = Bcy; scz[1][t] = Bcz; shh[1][t] = Bh;
    __syncthreads();
    for (int off = 128; off > 0; off >>= 1) {
        if (t < off) {
            #pragma unroll
            for (int q = 0; q < 2; q++) {
                const float dov = sd2[q][t + off];
                const int jov = sjj[q][t + off];
                if (dov < sd2[q][t] || (dov == sd2[q][t] && jov < sjj[q][t])) {
                    sd2[q][t] = dov; sjj[q][t] = jov;
                    scx[q][t] = scx[q][t + off];
                    scy[q][t] = scy[q][t + off];
                    scz[q][t] = scz[q][t + off];
                }
                shh[q][t] += shh[q][t + off];
            }
        }
        __syncthreads();
    }
    if (t == 0) {
        const float sg0 = (shh[0][0] & 1) ? -1.f : 1.f;
        out[i0] = sqrtf(sd2[0][0]) * sg0;
        out[N + 3 * i0 + 0] = scx[0][0];
        out[N + 3 * i0 + 1] = scy[0][0];
        out[N + 3 * i0 + 2] = scz[0][0];
        if (has1) {
            const float sg1 = (shh[1][0] & 1) ? -1.f : 1.f;
            out[i1] = sqrtf(sd2[1][0]) * sg1;
            out[N + 3 * i1 + 0] = scx[1][0];
            out[N + 3 * i1 + 1] = scy[1][0];
            out[N + 3 * i1 + 2] = scz[1][0];
        }
    }
}

extern "C" void kernel_launch(void* const* d_in, const int* in_sizes, int n_in,
                              void* d_out, int out_size, void* d_ws,
                              size_t ws_size, hipStream_t stream) {
    const float* p = (const float*)d_in[0];
    const float* v = (const float*)d_in[1];
    const int* f = (const int*)d_in[2];
    float* out = (float*)d_out;
    float* ws = (float*)d_ws;

    const int N = in_sizes[0] / 3;
    const int V = in_sizes[1] / 3;
    const int F = in_sizes[2] / 3;

    float4* fdat = (float4*)((char*)d_ws + 16);  // 16B offset keeps alignment

    vmean_kernel<<<1, 256, 0, stream>>>(v, V, ws);
    prep_kernel<<<(F + 255) / 256, 256, 0, stream>>>(v, f, fdat, F);
    sdf_main<<<(N + 1) / 2, 256, 0, stream>>>(p, fdat, ws, out, N, F);
}

// Round 3
// 42.729 us; speedup vs baseline: 2.0754x; 1.0827x over previous
//
#include <hip/hip_runtime.h>
#include <math.h>

#define TRI_EPS 1e-4f

// ---------- fused: per-face gather+precompute; block 0 also does mean(v) ----
// record j: [a.xyz, 1/|a-b|^2] [b.xyz, 1/|c-b|^2] [c.xyz, 1/|c-a|^2]
__global__ __launch_bounds__(256) void prep_kernel(
    const float* __restrict__ v, const int* __restrict__ f,
    float4* __restrict__ fdat, float* __restrict__ vm, int V, int F) {
    const int t = threadIdx.x;
    const int j = blockIdx.x * 256 + t;
    if (j < F) {
        const int i0 = f[3 * j + 0];
        const int i1 = f[3 * j + 1];
        const int i2 = f[3 * j + 2];
        const float ax = v[3 * i0 + 0], ay = v[3 * i0 + 1], az = v[3 * i0 + 2];
        const float bx = v[3 * i1 + 0], by = v[3 * i1 + 1], bz = v[3 * i1 + 2];
        const float cx = v[3 * i2 + 0], cy = v[3 * i2 + 1], cz = v[3 * i2 + 2];
        const float e1x = ax - bx, e1y = ay - by, e1z = az - bz;
        const float e2x = cx - bx, e2y = cy - by, e2z = cz - bz;
        const float e3x = cx - ax, e3y = cy - ay, e3z = cz - az;
        const float m1 = e1x * e1x + e1y * e1y + e1z * e1z;
        const float m2 = e2x * e2x + e2y * e2y + e2z * e2z;
        const float m3 = e3x * e3x + e3y * e3y + e3z * e3z;
        fdat[3 * j + 0] = make_float4(ax, ay, az, 1.f / m1);
        fdat[3 * j + 1] = make_float4(bx, by, bz, 1.f / m2);
        fdat[3 * j + 2] = make_float4(cx, cy, cz, 1.f / m3);
    }
    if (blockIdx.x == 0) {
        __shared__ float sx[256], sy[256], sz[256];
        float x = 0.f, y = 0.f, z = 0.f;
        for (int i = t; i < V; i += 256) {
            x += v[3 * i + 0];
            y += v[3 * i + 1];
            z += v[3 * i + 2];
        }
        sx[t] = x; sy[t] = y; sz[t] = z;
        __syncthreads();
        for (int off = 128; off > 0; off >>= 1) {
            if (t < off) {
                sx[t] += sx[t + off];
                sy[t] += sy[t + off];
                sz[t] += sz[t + off];
            }
            __syncthreads();
        }
        if (t == 0) {
            vm[0] = sx[0] / (float)V;
            vm[1] = sy[0] / (float)V;
            vm[2] = sz[0] / (float)V;
        }
    }
}

// all three edge distances (squared) + closest points + a-p vector.
// MUST be the single source of these expressions (main loop + epilogue both
// call it) so rounding is bit-identical everywhere.
struct FP {
    float d1, d2, d3;
    float x1, y1, z1, x2, y2, z2, x3, y3, z3;
    float apx, apy, apz;
};

__device__ __forceinline__ FP face_point(
    const float4 ra, const float4 rb, const float4 rc,
    const float e1x, const float e1y, const float e1z,
    const float e2x, const float e2y, const float e2z,
    const float e3x, const float e3y, const float e3z,
    const float px, const float py, const float pz) {
    FP r;
    const float ax = ra.x, ay = ra.y, az = ra.z;
    const float bx = rb.x, by = rb.y, bz = rb.z;
    const float cx = rc.x, cy = rc.y, cz = rc.z;
    r.apx = ax - px; r.apy = ay - py; r.apz = az - pz;
    const float cpx = cx - px, cpy = cy - py, cpz = cz - pz;

    float s1 = (r.apx * e1x + r.apy * e1y + r.apz * e1z) * ra.w;
    s1 = fminf(fmaxf(s1, 0.f), 1.f);
    const float o1 = 1.f - s1;
    r.x1 = s1 * bx + o1 * ax;
    r.y1 = s1 * by + o1 * ay;
    r.z1 = s1 * bz + o1 * az;
    float ux = r.x1 - px, uy = r.y1 - py, uz = r.z1 - pz;
    r.d1 = ux * ux + uy * uy + uz * uz;

    float s2 = (cpx * e2x + cpy * e2y + cpz * e2z) * rb.w;
    s2 = fminf(fmaxf(s2, 0.f), 1.f);
    const float o2 = 1.f - s2;
    r.x2 = s2 * bx + o2 * cx;
    r.y2 = s2 * by + o2 * cy;
    r.z2 = s2 * bz + o2 * cz;
    ux = r.x2 - px; uy = r.y2 - py; uz = r.z2 - pz;
    r.d2 = ux * ux + uy * uy + uz * uz;

    float s3 = (cpx * e3x + cpy * e3y + cpz * e3z) * rc.w;
    s3 = fminf(fmaxf(s3, 0.f), 1.f);
    const float o3 = 1.f - s3;
    r.x3 = s3 * ax + o3 * cx;
    r.y3 = s3 * ay + o3 * cy;
    r.z3 = s3 * az + o3 * cz;
    ux = r.x3 - px; uy = r.y3 - py; uz = r.z3 - pz;
    r.d3 = ux * ux + uy * uy + uz * uz;
    return r;
}

__device__ __forceinline__ void pair_update(
    const float4 ra, const float4 rb, const float4 rc,
    const float e1x, const float e1y, const float e1z,
    const float e2x, const float e2y, const float e2z,
    const float e3x, const float e3y, const float e3z,
    const float px, const float py, const float pz,
    const float dx, const float dy, const float dz, const int j,
    float& bd2, int& bid, int& hits) {
    const FP r = face_point(ra, rb, rc, e1x, e1y, e1z, e2x, e2y, e2z,
                            e3x, e3y, e3z, px, py, pz);
    // first-occurrence argmin over edges, then over faces; packed id
    float fd2 = r.d1; int eid = 0;
    if (r.d2 < fd2) { fd2 = r.d2; eid = 1; }
    if (r.d3 < fd2) { fd2 = r.d3; eid = 2; }
    if (fd2 < bd2) { bd2 = fd2; bid = (j << 2) | eid; }

    // Moller-Trumbore, division-free (bit-identical to round-2 version).
    const float pvx = dy * e3z - dz * e3y;
    const float pvy = dz * e3x - dx * e3z;
    const float pvz = dx * e3y - dy * e3x;
    const float det = -(e1x * pvx + e1y * pvy + e1z * pvz);
    const float tu = -(r.apx * pvx + r.apy * pvy + r.apz * pvz);
    const float qvx = r.apy * e1z - r.apz * e1y;
    const float qvy = r.apz * e1x - r.apx * e1z;
    const float qvz = r.apx * e1y - r.apy * e1x;
    const float td = dx * qvx + dy * qvy + dz * qvz;
    const float tn = e3x * qvx + e3y * qvy + e3z * qvz;
    const float adet = fabsf(det);
    const float sd = (det > 0.f) ? 1.f : -1.f;
    const float su = tu * sd;
    const float sq = td * sd;
    const float st = tn * sd;
    if (adet > TRI_EPS && su >= 0.f && su <= adet && sq >= 0.f &&
        (su + sq) <= adet && st > TRI_EPS * adet)
        hits++;
}

__global__ __launch_bounds__(256) void sdf_main(
    const float* __restrict__ p, const float4* __restrict__ fd,
    const float* __restrict__ vm, float* __restrict__ out, int N, int F) {
    const int t = threadIdx.x;
    const int i0 = blockIdx.x * 2;
    const int i1 = i0 + 1;
    const bool has1 = (i1 < N);

    const float vmx = vm[0], vmy = vm[1], vmz = vm[2];
    const float p0x = p[3 * i0 + 0], p0y = p[3 * i0 + 1], p0z = p[3 * i0 + 2];
    const float p1x = has1 ? p[3 * i1 + 0] : 0.f;
    const float p1y = has1 ? p[3 * i1 + 1] : 0.f;
    const float p1z = has1 ? p[3 * i1 + 2] : 0.f;
    const float d0x = vmx - p0x, d0y = vmy - p0y, d0z = vmz - p0z;
    const float d1x = vmx - p1x, d1y = vmy - p1y, d1z = vmz - p1z;

    float Ad2 = INFINITY; int Aid = 0x7fffffff; int Ah = 0;
    float Bd2 = INFINITY; int Bid = 0x7fffffff; int Bh = 0;

    // software-pipelined face loop: prefetch j+256 before processing j
    int j = t;
    bool valid = (j < F);
    float4 ra, rb, rc;
    if (valid) {
        ra = fd[3 * j + 0];
        rb = fd[3 * j + 1];
        rc = fd[3 * j + 2];
    }
    while (valid) {
        const int jn = j + 256;
        const bool vn = (jn < F);
        float4 na, nb, nc;
        if (vn) {
            na = fd[3 * jn + 0];
            nb = fd[3 * jn + 1];
            nc = fd[3 * jn + 2];
        }
        const float e1x = ra.x - rb.x, e1y = ra.y - rb.y, e1z = ra.z - rb.z;
        const float e2x = rc.x - rb.x, e2y = rc.y - rb.y, e2z = rc.z - rb.z;
        const float e3x = rc.x - ra.x, e3y = rc.y - ra.y, e3z = rc.z - ra.z;

        pair_update(ra, rb, rc, e1x, e1y, e1z, e2x, e2y, e2z, e3x, e3y, e3z,
                    p0x, p0y, p0z, d0x, d0y, d0z, j, Ad2, Aid, Ah);
        pair_update(ra, rb, rc, e1x, e1y, e1z, e2x, e2y, e2z, e3x, e3y, e3z,
                    p1x, p1y, p1z, d1x, d1y, d1z, j, Bd2, Bid, Bh);

        j = jn; valid = vn;
        ra = na; rb = nb; rc = nc;
    }

    __shared__ float sd2[2][256];
    __shared__ int sid[2][256];
    __shared__ int shh[2][256];
    sd2[0][t] = Ad2; sid[0][t] = Aid; shh[0][t] = Ah;
    sd2[1][t] = Bd2; sid[1][t] = Bid; shh[1][t] = Bh;
    __syncthreads();
    for (int off = 128; off > 0; off >>= 1) {
        if (t < off) {
            #pragma unroll
            for (int q = 0; q < 2; q++) {
                const float dov = sd2[q][t + off];
                const int iov = sid[q][t + off];
                if (dov < sd2[q][t] || (dov == sd2[q][t] && iov < sid[q][t])) {
                    sd2[q][t] = dov;
                    sid[q][t] = iov;
                }
                shh[q][t] += shh[q][t + off];
            }
        }
        __syncthreads();
    }

    // epilogue: threads 0,1 recompute the winning closest point (identical
    // arithmetic via face_point) and write outputs.
    if (t < 2) {
        const int i = i0 + t;
        if (i < N) {
            const float px = t ? p1x : p0x;
            const float py = t ? p1y : p0y;
            const float pz = t ? p1z : p0z;
            const int bid = sid[t][0];
            const int jw = bid >> 2;
            const int eid = bid & 3;
            const float4 wa = fd[3 * jw + 0];
            const float4 wb = fd[3 * jw + 1];
            const float4 wc = fd[3 * jw + 2];
            const float e1x = wa.x - wb.x, e1y = wa.y - wb.y, e1z = wa.z - wb.z;
            const float e2x = wc.x - wb.x, e2y = wc.y - wb.y, e2z = wc.z - wb.z;
            const float e3x = wc.x - wa.x, e3y = wc.y - wa.y, e3z = wc.z - wa.z;
            const FP r = face_point(wa, wb, wc, e1x, e1y, e1z, e2x, e2y, e2z,
                                    e3x, e3y, e3z, px, py, pz);
            float clx = r.x1, cly = r.y1, clz = r.z1;
            if (eid == 1) { clx = r.x2; cly = r.y2; clz = r.z2; }
            if (eid == 2) { clx = r.x3; cly = r.y3; clz = r.z3; }
            const float d = sqrtf(sd2[t][0]);
            out[i] = (shh[t][0] & 1) ? -d : d;
            out[N + 3 * i + 0] = clx;
            out[N + 3 * i + 1] = cly;
            out[N + 3 * i + 2] = clz;
        }
    }
}

extern "C" void kernel_launch(void* const* d_in, const int* in_sizes, int n_in,
                              void* d_out, int out_size, void* d_ws,
                              size_t ws_size, hipStream_t stream) {
    const float* p = (const float*)d_in[0];
    const float* v = (const float*)d_in[1];
    const int* f = (const int*)d_in[2];
    float* out = (float*)d_out;
    float* ws = (float*)d_ws;

    const int N = in_sizes[0] / 3;
    const int V = in_sizes[1] / 3;
    const int F = in_sizes[2] / 3;

    float4* fdat = (float4*)((char*)d_ws + 16);

    prep_kernel<<<(F + 255) / 256, 256, 0, stream>>>(v, f, fdat, ws, V, F);
    sdf_main<<<(N + 1) / 2, 256, 0, stream>>>(p, fdat, ws, out, N, F);
}